// Round 4
// baseline (881.401 us; speedup 1.0000x reference)
//
#include <hip/hip_runtime.h>
#include <math.h>

// ---------------- problem constants ----------------
#define NI    100000
#define KSEL  1000
#define NCOL2 640          // packed cols: 512 interleaved Wa/Wb pairs | 4 Wcls | 15 Wr | 109 pad
#define HBINS 2048         // radix histogram bins (max) per selection column
#define SELY  16           // y-grid for hist/collect

// ---------------- d_out layout (floats) ----------------
#define OUT_FS   0
#define OUT_YP   400000
#define OUT_YH   400004
#define OUT_REF  400005
#define OUT_LOSS 900005

// ---------------- workspace layout (float offsets) ----------------
#define OFF_DET    0                 // det_logit N*4
#define OFF_CLS    400000            // cls_score N*4
#define OFF_REF0   800000            // softmax(h@Wr0+br0) N*5
#define OFF_REF1   1300000           // softmax(h@Wr1+br1) N*5
#define OFF_MEAN   1800000           // mean_score N
#define OFF_WPT    1900000           // bf16 packed W^T [640][512] = 327680 ushorts
#define OFF_BPACK  2063840           // packed bias [640]
#define OFF_SCAL   2064480           // 128 scalar slots
#define OFF_SELIDX 2064608           // 15*1000 ints
#define OFF_HIST   2079608           // 15*2048 u32

// scalar slots (index into u32/f32/i32 view of ws+OFF_SCAL)
#define SC_SUMEXP 0     // f[4] det softmax denominator
#define SC_YPROB  4     // f[4]
#define SC_FSMIN  8     // u[4] encoded min of final_score per class
#define SC_FSMAX  12    // u[4]
#define SC_THR    16    // f[4] norm-0.5 threshold on raw fs
#define SC_INCL   20    // i[5]
#define SC_NUM    25    // f[3] CE numerators
#define SC_CNT    28    // i[15] selected counts
#define SC_PREFIX 43    // u[15] accumulated radix prefix -> final = exact k-th key
#define SC_RESTK  58    // u[15] remaining k inside current prefix
#define SC_HDONE  88    // u[15] hist done-counters (accumulate across 3 passes)
#define SC_FDONE  103   // u[1] final_kernel done-counter

typedef short short8 __attribute__((ext_vector_type(8)));
typedef float f32x4 __attribute__((ext_vector_type(4)));

__device__ __forceinline__ unsigned fenc(float x) {
    unsigned u = __float_as_uint(x);
    return (u & 0x80000000u) ? ~u : (u | 0x80000000u);
}
__device__ __forceinline__ unsigned short f2bf(float f) {
    unsigned u = __float_as_uint(f);
    return (unsigned short)((u + 0x7FFFu + ((u >> 16) & 1u)) >> 16);
}

// ================= kernel 1: pack weights bf16 col-major, biases, init scalars/hist =================
__global__ __launch_bounds__(256) void prep_kernel(
    const float* __restrict__ Wa, const float* __restrict__ Wb,
    const float* __restrict__ Wcls, const float* __restrict__ Wr,
    const float* __restrict__ ba, const float* __restrict__ bb,
    const float* __restrict__ bcls, const float* __restrict__ br,
    float* __restrict__ ws)
{
    const int tid0 = blockIdx.x * 256 + threadIdx.x;   // grid 1280*256 = 327680 threads
    unsigned short* wpT = (unsigned short*)(ws + OFF_WPT);
    if (tid0 < NCOL2 * 512) {
        const int c = tid0 >> 9, k = tid0 & 511;
        float v = 0.f;
        if (c < 512)      { const int j = c >> 1; v = (c & 1) ? Wb[k*256 + j] : Wa[k*256 + j]; }
        else if (c < 516)   v = Wcls[k*4 + (c - 512)];
        else if (c < 531) { const int q = c - 516; v = Wr[((q/5)*512 + k)*5 + (q%5)]; }
        wpT[tid0] = f2bf(v);
    }
    if (tid0 < NCOL2) {
        float v = 0.f; const int c = tid0;
        if (c < 512)      v = (c & 1) ? bb[c >> 1] : ba[c >> 1];
        else if (c < 516) v = bcls[c - 512];
        else if (c < 531) v = br[c - 516];
        ws[OFF_BPACK + c] = v;
    }
    if (tid0 < 128) {
        unsigned* su = (unsigned*)(ws + OFF_SCAL);
        unsigned v = 0u;
        if (tid0 >= SC_FSMIN && tid0 < SC_FSMIN + 4)   v = 0xFFFFFFFFu;
        if (tid0 >= SC_RESTK && tid0 < SC_RESTK + 15)  v = (unsigned)KSEL;
        su[tid0] = v;
    }
    unsigned* hist = (unsigned*)(ws + OFF_HIST);
    if (tid0 < 15 * HBINS) hist[tid0] = 0u;
}

// ================= kernel 2: bf16 MFMA GEMM, A-tile fully LDS-resident =================
// grid 782 x 256 thr, 1 block/CU (157 KB LDS). Block owns 128 rows. cb=0 streams A from
// global (f32->bf16) into the resident LDS tile while computing; cb=1..4 reuse it free.
// cb<4: gate pairs -> det partial in LDS. cb==4: 19 small cols -> cls/ref softmaxes.
__global__ __launch_bounds__(256) void gemm_mfma(
    const float* __restrict__ h, const unsigned short* __restrict__ wpT,
    const float* __restrict__ bpack, const float* __restrict__ Wc,
    const float* __restrict__ bc,
    float* __restrict__ det_logit, float* __restrict__ det_sumexp,
    float* __restrict__ cls_score, float* __restrict__ ref0,
    float* __restrict__ ref1, float* __restrict__ out_ref2)
{
    __shared__ unsigned short Abig[128 * 520];   // 133,120 B: [row][k], +8 ushort pad
    __shared__ unsigned short Bls[128 * 40];     // 10,240 B: [col][32k + pad8]
    __shared__ float slog[128 * 20];             // 10,240 B
    __shared__ float sdet[128][4];               // 2,048 B
    __shared__ float sWcb[256];                  // 1,024 B
    __shared__ float sbias[128];                 // 512 B
    __shared__ float sred[4][4];                 // 64 B   -> total 157,248 B

    const int tid = threadIdx.x;
    const int bm0 = blockIdx.x * 128;
    const int lane = tid & 63;
    const int w = tid >> 6;
    const int wm = (w >> 1) * 64, wn = (w & 1) * 64;
    const int lrow = lane & 15, lq = lane >> 4;

    if (tid < 128) { sdet[tid][0] = 0.f; sdet[tid][1] = 0.f; sdet[tid][2] = 0.f; sdet[tid][3] = 0.f; }

    for (int cb = 0; cb < 5; ++cb) {
        const int n0 = cb * 128;
        __syncthreads();   // prior epilogue done before overwriting sbias/sWcb/Bls
        if (cb < 4) sWcb[tid] = Wc[(n0 >> 1) * 4 + tid];
        if (tid < 128) sbias[tid] = bpack[n0 + tid];

        f32x4 acc[4][4];
        #pragma unroll
        for (int mt = 0; mt < 4; ++mt)
            #pragma unroll
            for (int nt = 0; nt < 4; ++nt) acc[mt][nt] = (f32x4)0.f;

        float4 aR[4]; uint4 bR[2];
        if (cb == 0) {
            #pragma unroll
            for (int it = 0; it < 4; ++it) {
                const int q = tid + it*256, row = q >> 3, k0 = (q & 7) * 4, grow = bm0 + row;
                aR[it] = (grow < NI) ? *(const float4*)&h[(size_t)grow * 512 + k0]
                                     : make_float4(0.f, 0.f, 0.f, 0.f);
            }
        }
        #pragma unroll
        for (int it = 0; it < 2; ++it) {
            const int q = tid + it*256, col = q >> 2, k0 = (q & 3) * 8;
            bR[it] = *(const uint4*)&wpT[(size_t)(n0 + col) * 512 + k0];
        }

        for (int kc = 0; kc < 512; kc += 32) {
            if (cb == 0) {
                #pragma unroll
                for (int it = 0; it < 4; ++it) {
                    const int q = tid + it*256, row = q >> 3, k0 = (q & 7) * 4;
                    ushort4 pk;
                    pk.x = f2bf(aR[it].x); pk.y = f2bf(aR[it].y);
                    pk.z = f2bf(aR[it].z); pk.w = f2bf(aR[it].w);
                    *(ushort4*)&Abig[row * 520 + kc + k0] = pk;
                }
            }
            #pragma unroll
            for (int it = 0; it < 2; ++it) {
                const int q = tid + it*256, col = q >> 2, k0 = (q & 3) * 8;
                *(uint4*)&Bls[col * 40 + k0] = bR[it];
            }
            __syncthreads();
            const int kn = kc + 32;
            if (kn < 512) {   // prefetch next chunk (overlaps MFMA)
                if (cb == 0) {
                    #pragma unroll
                    for (int it = 0; it < 4; ++it) {
                        const int q = tid + it*256, row = q >> 3, k0 = (q & 7) * 4, grow = bm0 + row;
                        aR[it] = (grow < NI) ? *(const float4*)&h[(size_t)grow * 512 + kn + k0]
                                             : make_float4(0.f, 0.f, 0.f, 0.f);
                    }
                }
                #pragma unroll
                for (int it = 0; it < 2; ++it) {
                    const int q = tid + it*256, col = q >> 2, k0 = (q & 3) * 8;
                    bR[it] = *(const uint4*)&wpT[(size_t)(n0 + col) * 512 + kn + k0];
                }
            }
            short8 af[4], bfr[4];
            #pragma unroll
            for (int mt = 0; mt < 4; ++mt) af[mt]  = *(const short8*)&Abig[(wm + mt*16 + lrow) * 520 + kc + lq*8];
            #pragma unroll
            for (int nt = 0; nt < 4; ++nt) bfr[nt] = *(const short8*)&Bls[(wn + nt*16 + lrow) * 40 + lq*8];
            #pragma unroll
            for (int mt = 0; mt < 4; ++mt)
                #pragma unroll
                for (int nt = 0; nt < 4; ++nt)
                    acc[mt][nt] = __builtin_amdgcn_mfma_f32_16x16x32_bf16(af[mt], bfr[nt], acc[mt][nt], 0, 0, 0);
            __syncthreads();
        }

        if (cb < 4) {
            // gated attention -> det partial; C/D layout col=lane&15, row=lq*4+reg
            #pragma unroll
            for (int mt = 0; mt < 4; ++mt) {
                #pragma unroll
                for (int reg = 0; reg < 4; ++reg) {
                    float c0 = 0.f, c1 = 0.f, c2 = 0.f, c3 = 0.f;
                    #pragma unroll
                    for (int nt = 0; nt < 4; ++nt) {
                        const int cl = wn + nt*16 + lrow;       // local col; parity == lane parity
                        const float v = acc[mt][nt][reg] + sbias[cl];
                        const float p = __shfl_xor(v, 1);
                        const float ve = (lane & 1) ? p : v;    // Wa logit
                        const float vo = (lane & 1) ? v : p;    // Wb logit
                        const float e2 = __expf(2.f * ve);
                        const float gate = (1.f - 2.f / (e2 + 1.f)) * (1.f / (1.f + __expf(-vo)));
                        if (!(lane & 1)) {                      // even lane owns the pair
                            const int j = cl >> 1;
                            c0 += gate * sWcb[j*4+0]; c1 += gate * sWcb[j*4+1];
                            c2 += gate * sWcb[j*4+2]; c3 += gate * sWcb[j*4+3];
                        }
                    }
                    #pragma unroll
                    for (int m = 1; m <= 8; m <<= 1) {
                        c0 += __shfl_xor(c0, m); c1 += __shfl_xor(c1, m);
                        c2 += __shfl_xor(c2, m); c3 += __shfl_xor(c3, m);
                    }
                    if ((lane & 15) == 0) {
                        const int rl = wm + mt*16 + lq*4 + reg;
                        atomicAdd(&sdet[rl][0], c0); atomicAdd(&sdet[rl][1], c1);
                        atomicAdd(&sdet[rl][2], c2); atomicAdd(&sdet[rl][3], c3);
                    }
                }
            }
        } else {
            if (wn == 0) {   // waves 0,2 hold the 19 real columns (512..530)
                #pragma unroll
                for (int mt = 0; mt < 4; ++mt)
                    #pragma unroll
                    for (int reg = 0; reg < 4; ++reg)
                        #pragma unroll
                        for (int nt = 0; nt < 2; ++nt) {
                            const int cl = nt*16 + lrow;
                            if (cl < 19) {
                                const int row = wm + mt*16 + lq*4 + reg;
                                slog[row * 20 + cl] = acc[mt][nt][reg] + sbias[cl];
                            }
                        }
            }
            __syncthreads();
            if (tid < 128) {
                const int grow = bm0 + tid;
                if (grow < NI) {
                    float L[19];
                    #pragma unroll
                    for (int q = 0; q < 19; ++q) L[q] = slog[tid * 20 + q];
                    {   // cls softmax (cols 0..3)
                        float m = fmaxf(fmaxf(L[0], L[1]), fmaxf(L[2], L[3]));
                        float e0 = __expf(L[0]-m), e1 = __expf(L[1]-m), e2 = __expf(L[2]-m), e3 = __expf(L[3]-m);
                        const float inv = 1.f / (e0 + e1 + e2 + e3);
                        cls_score[(size_t)grow*4+0] = e0*inv; cls_score[(size_t)grow*4+1] = e1*inv;
                        cls_score[(size_t)grow*4+2] = e2*inv; cls_score[(size_t)grow*4+3] = e3*inv;
                    }
                    #pragma unroll
                    for (int r = 0; r < 3; ++r) {
                        float m = L[4+5*r];
                        #pragma unroll
                        for (int e = 1; e < 5; ++e) m = fmaxf(m, L[4+5*r+e]);
                        float ev[5]; float s = 0.f;
                        #pragma unroll
                        for (int e = 0; e < 5; ++e) { ev[e] = __expf(L[4+5*r+e] - m); s += ev[e]; }
                        const float inv = 1.f / s;
                        float* dst = (r == 0) ? ref0 : ((r == 1) ? ref1 : out_ref2);
                        #pragma unroll
                        for (int e = 0; e < 5; ++e) dst[(size_t)grow*5+e] = ev[e] * inv;
                    }
                }
            }
        }
    }
    __syncthreads();

    // det_logit write + per-class exp-sum partial (fused det softmax denominator)
    float e0 = 0.f, e1 = 0.f, e2 = 0.f, e3 = 0.f;
    if (tid < 128) {
        const int grow = bm0 + tid;
        const float d0 = sdet[tid][0] + bc[0];
        const float d1 = sdet[tid][1] + bc[1];
        const float d2 = sdet[tid][2] + bc[2];
        const float d3 = sdet[tid][3] + bc[3];
        if (grow < NI) {
            float4 dv = make_float4(d0, d1, d2, d3);
            *(float4*)&det_logit[(size_t)grow * 4] = dv;
            e0 = __expf(d0); e1 = __expf(d1); e2 = __expf(d2); e3 = __expf(d3);
        }
    }
    #pragma unroll
    for (int m = 1; m < 64; m <<= 1) {
        e0 += __shfl_xor(e0, m); e1 += __shfl_xor(e1, m);
        e2 += __shfl_xor(e2, m); e3 += __shfl_xor(e3, m);
    }
    if (lane == 0) { sred[w][0] = e0; sred[w][1] = e1; sred[w][2] = e2; sred[w][3] = e3; }
    __syncthreads();
    if (tid < 4)
        atomicAdd(&det_sumexp[tid], sred[0][tid] + sred[1][tid] + sred[2][tid] + sred[3][tid]);
}

// ================= kernel 3: final_score + fused scalars (last-block trick) =================
__global__ __launch_bounds__(256) void final_kernel(const float* __restrict__ det_logit,
        const float* __restrict__ cls_score, const int* __restrict__ label,
        float* __restrict__ ws_scal, float* __restrict__ out_fs,
        float* __restrict__ mean_sc, float* __restrict__ out)
{
    __shared__ float ssum[4][4], smin[4][4], smax[4][4];
    __shared__ int isLast;
    float* sf = ws_scal; unsigned* su = (unsigned*)ws_scal; int* si = (int*)ws_scal;
    const float* det_sumexp = sf + SC_SUMEXP;
    const int i = blockIdx.x * 256 + threadIdx.x;
    const bool valid = i < NI;
    float f[4]; float tot = 0.f;
    #pragma unroll
    for (int c = 0; c < 4; ++c) {
        float v = 0.f;
        if (valid) {
            const float ds = __expf(det_logit[(size_t)i*4+c]) / det_sumexp[c];
            v = cls_score[(size_t)i*4+c] * ds;
            out_fs[(size_t)i*4+c] = v;
        }
        f[c] = v; tot += v;
    }
    if (valid) mean_sc[i] = 0.25f * tot;
    float sm[4], mn[4], mx[4];
    #pragma unroll
    for (int c = 0; c < 4; ++c) {
        sm[c] = f[c];
        mn[c] = valid ? f[c] : 3.4e38f;
        mx[c] = valid ? f[c] : -3.4e38f;
    }
    #pragma unroll
    for (int c = 0; c < 4; ++c)
        #pragma unroll
        for (int m = 1; m < 64; m <<= 1) {
            sm[c] += __shfl_xor(sm[c], m, 64);
            mn[c] = fminf(mn[c], __shfl_xor(mn[c], m, 64));
            mx[c] = fmaxf(mx[c], __shfl_xor(mx[c], m, 64));
        }
    const int w = threadIdx.x >> 6;
    if ((threadIdx.x & 63) == 0) {
        #pragma unroll
        for (int c = 0; c < 4; ++c) { ssum[w][c] = sm[c]; smin[w][c] = mn[c]; smax[w][c] = mx[c]; }
    }
    __syncthreads();
    if (threadIdx.x < 4) {
        const int c = threadIdx.x;
        float S = 0.f, MN = 3.4e38f, MX = -3.4e38f;
        #pragma unroll
        for (int w2 = 0; w2 < 4; ++w2) {
            S += ssum[w2][c]; MN = fminf(MN, smin[w2][c]); MX = fmaxf(MX, smax[w2][c]);
        }
        atomicAdd(&sf[SC_YPROB + c], S);
        atomicMin(&su[SC_FSMIN + c], fenc(MN));
        atomicMax(&su[SC_FSMAX + c], fenc(MX));
    }
    __threadfence();
    if (threadIdx.x == 0) {
        const unsigned old = atomicAdd(&su[SC_FDONE], 1u);
        isLast = (old == gridDim.x - 1) ? 1 : 0;
    }
    __syncthreads();
    if (isLast && threadIdx.x == 0) {
        float best = -1.f; int arg = 0;
        for (int c = 0; c < 4; ++c) {
            float v = atomicAdd(&sf[SC_YPROB + c], 0.f);   // coherent read
            v = fminf(fmaxf(v, 1e-10f), 1.f - 1e-10f);
            out[OUT_YP + c] = v;
            if (v > best) { best = v; arg = c; }
        }
        out[OUT_YH] = (float)arg;
        for (int c = 0; c < 4; ++c) {
            const unsigned ue = atomicOr(&su[SC_FSMIN + c], 0u);
            const unsigned ux = atomicOr(&su[SC_FSMAX + c], 0u);
            const float mnv = (ue & 0x80000000u) ? __uint_as_float(ue & 0x7FFFFFFFu) : __uint_as_float(~ue);
            const float mxv = (ux & 0x80000000u) ? __uint_as_float(ux & 0x7FFFFFFFu) : __uint_as_float(~ux);
            sf[SC_THR + c] = mnv + 0.5f * (mxv - mnv);
        }
        const int l0 = label[0], l1 = label[1];
        for (int c = 0; c < 4; ++c) si[SC_INCL + c] = (l0 == c || l1 == c) ? 1 : 0;
        si[SC_INCL + 4] = 1;
    }
}

// ---- selection column accessor: b 0..3 fs, 4 mean(bottom), 5..9 ref0, 10..14 ref1
__device__ __forceinline__ float sel_value(int b, int i, const float* fs, const float* mean,
                                           const float* r0, const float* r1) {
    if (b < 4)  return fs[(size_t)i*4 + b];
    if (b == 4) return mean[i];
    if (b < 10) return r0[(size_t)i*5 + (b-5)];
    return r1[(size_t)i*5 + (b-10)];
}

// ================= kernel 4: radix histogram pass + fused suffix-scan (last-block) =================
__global__ __launch_bounds__(256) void hist_kernel(const float* __restrict__ fs,
        const float* __restrict__ mean, const float* __restrict__ r0, const float* __restrict__ r1,
        unsigned* __restrict__ hist, float* __restrict__ ws_scal, int shift, int width)
{
    const int b = blockIdx.x;
    unsigned* su = (unsigned*)ws_scal;
    const int* si = (const int*)ws_scal;
    const int c = (b < 4) ? b : ((b == 4) ? -1 : ((b < 10) ? b - 5 : b - 10));
    if (c >= 0 && !si[SC_INCL + c]) return;
    __shared__ unsigned lh[HBINS];
    __shared__ unsigned csum[256];
    __shared__ int isLast;
    unsigned* hh = hist + (size_t)b * HBINS;
    const int nbins = 1 << width;
    for (int t = threadIdx.x; t < nbins; t += 256) lh[t] = 0u;
    __syncthreads();
    const int pb = shift + width;
    const unsigned prefix = su[SC_PREFIX + b];
    const unsigned mask = (unsigned)(nbins - 1);
    for (int i = blockIdx.y * 256 + threadIdx.x; i < NI; i += SELY * 256) {
        const float v = sel_value(b, i, fs, mean, r0, r1);
        const unsigned u = fenc(b == 4 ? -v : v);
        if (pb >= 32 || (u >> pb) == prefix)
            atomicAdd(&lh[(u >> shift) & mask], 1u);
    }
    __syncthreads();
    for (int t = threadIdx.x; t < nbins; t += 256)
        if (lh[t]) atomicAdd(&hh[t], lh[t]);
    __threadfence();
    if (threadIdx.x == 0) {
        const unsigned old = atomicAdd(&su[SC_HDONE + b], 1u);
        isLast = (((old + 1) % SELY) == 0) ? 1 : 0;
    }
    __syncthreads();
    if (!isLast) return;
    // ---- fused scan: pull bins coherently (and zero them for the next pass) ----
    for (int t = threadIdx.x; t < nbins; t += 256) lh[t] = atomicExch(&hh[t], 0u);
    __syncthreads();
    const int chunk = nbins >> 8;
    {
        unsigned s = 0;
        const int base = threadIdx.x * chunk;
        for (int j = 0; j < chunk; ++j) s += lh[base + j];
        csum[threadIdx.x] = s;
    }
    __syncthreads();
    if (threadIdx.x == 0) {
        const unsigned K = su[SC_RESTK + b];
        unsigned running = 0; unsigned found = 0; unsigned rem = K;
        int t;
        for (t = 255; t >= 0; --t) {
            if (running + csum[t] >= K) break;
            running += csum[t];
        }
        if (t < 0) t = 0;
        for (int j = chunk - 1; j >= 0; --j) {
            const int idx = t * chunk + j;
            const unsigned cc = lh[idx];
            if (running + cc >= K) { found = (unsigned)idx; rem = K - running; break; }
            running += cc;
        }
        su[SC_RESTK + b] = rem;
        su[SC_PREFIX + b] = (su[SC_PREFIX + b] << width) | found;
    }
}

// ================= kernel 5: collect selected indices =================
__global__ __launch_bounds__(256) void collect_kernel(const float* __restrict__ fs,
        const float* __restrict__ mean, const float* __restrict__ r0, const float* __restrict__ r1,
        float* __restrict__ ws_scal, int* __restrict__ sel_idx)
{
    const int b = blockIdx.x;
    unsigned* su = (unsigned*)ws_scal; int* si = (int*)ws_scal; float* sf = ws_scal;
    const int c = (b < 4) ? b : ((b == 4) ? -1 : ((b < 10) ? b - 5 : b - 10));
    if (c >= 0 && !si[SC_INCL + c]) return;
    const unsigned kth = su[SC_PREFIX + b];   // after 3 passes = exact k-th key
    const float extra = (b < 4) ? sf[SC_THR + b] : 0.5f;
    for (int i = blockIdx.y * 256 + threadIdx.x; i < NI; i += SELY * 256) {
        const float v = sel_value(b, i, fs, mean, r0, r1);
        const unsigned u = fenc(b == 4 ? -v : v);
        const bool cond = (b == 4) ? (v < 0.5f) : (v > extra);
        if (u >= kth && cond) {
            const int pos = atomicAdd(&si[SC_CNT + b], 1);
            if (pos < KSEL) sel_idx[b * KSEL + pos] = i;
        }
    }
}

// ================= kernel 6: CE over selected candidates (one wave per slot) =================
__global__ __launch_bounds__(256) void ce_kernel(const float* __restrict__ h,
        const float* __restrict__ Wr, const float* __restrict__ br,
        const int* __restrict__ sel_idx, float* __restrict__ ws_scal)
{
    const int* si = (const int*)ws_scal;
    float* sf = ws_scal;
    const int lane = threadIdx.x & 63;
    const int wid = (blockIdx.x * blockDim.x + threadIdx.x) >> 6;
    const int nw = (gridDim.x * blockDim.x) >> 6;
    float l0a = 0.f, l1a = 0.f, l2a = 0.f;
    for (int slot = wid; slot < 15 * KSEL; slot += nw) {
        const int b = slot / KSEL;
        const int j = slot - b * KSEL;
        const int cnt = min(si[SC_CNT + b], KSEL);
        if (j >= cnt) continue;
        const int i = sel_idx[b * KSEL + j];
        const int g = (b < 5) ? 0 : ((b < 10) ? 1 : 2);
        const int tgt = (b < 4) ? b : ((b == 4) ? 4 : ((b < 10) ? (b - 5) : (b - 10)));
        const float* hr = h + (size_t)i * 512;
        const float* wr = Wr + (size_t)g * 512 * 5;
        const int d0 = lane * 8;
        const float4 va = *(const float4*)&hr[d0];
        const float4 vb = *(const float4*)&hr[d0 + 4];
        const float hv[8] = {va.x, va.y, va.z, va.w, vb.x, vb.y, vb.z, vb.w};
        float acc[5] = {0.f, 0.f, 0.f, 0.f, 0.f};
        #pragma unroll
        for (int t = 0; t < 8; ++t) {
            const float* row = wr + (size_t)(d0 + t) * 5;
            #pragma unroll
            for (int e = 0; e < 5; ++e) acc[e] += hv[t] * row[e];
        }
        #pragma unroll
        for (int e = 0; e < 5; ++e)
            #pragma unroll
            for (int m = 1; m < 64; m <<= 1) acc[e] += __shfl_xor(acc[e], m, 64);
        if (lane == 0) {
            float l[5];
            #pragma unroll
            for (int e = 0; e < 5; ++e) l[e] = acc[e] + br[g * 5 + e];
            float mx = l[0];
            #pragma unroll
            for (int e = 1; e < 5; ++e) mx = fmaxf(mx, l[e]);
            float s = 0.f;
            #pragma unroll
            for (int e = 0; e < 5; ++e) s += __expf(l[e] - mx);
            const float ce = logf(s) + mx - l[tgt];
            if (g == 0) l0a += ce; else if (g == 1) l1a += ce; else l2a += ce;
        }
    }
    if (lane == 0) {
        if (l0a != 0.f) atomicAdd(&sf[SC_NUM + 0], l0a);
        if (l1a != 0.f) atomicAdd(&sf[SC_NUM + 1], l1a);
        if (l2a != 0.f) atomicAdd(&sf[SC_NUM + 2], l2a);
    }
}

// ================= kernel 7: finalize instance_loss =================
__global__ void loss_kernel(const float* __restrict__ ws_scal, float* __restrict__ out)
{
    if (blockIdx.x == 0 && threadIdx.x == 0) {
        const int* si = (const int*)ws_scal;
        float loss = 0.f;
        for (int g = 0; g < 3; ++g) {
            int den = 0;
            for (int b = g * 5; b < g * 5 + 5; ++b) den += min(si[SC_CNT + b], KSEL);
            loss += ws_scal[SC_NUM + g] / (float)(den > 1 ? den : 1);
        }
        out[OUT_LOSS] = loss;
    }
}

// ================= launch =================
extern "C" void kernel_launch(void* const* d_in, const int* in_sizes, int n_in,
                              void* d_out, int out_size, void* d_ws, size_t ws_size,
                              hipStream_t stream)
{
    const float* h    = (const float*)d_in[0];
    const int*   lab  = (const int*)d_in[1];
    const float* Wa   = (const float*)d_in[2];
    const float* ba   = (const float*)d_in[3];
    const float* Wb   = (const float*)d_in[4];
    const float* bb   = (const float*)d_in[5];
    const float* Wc   = (const float*)d_in[6];
    const float* bc   = (const float*)d_in[7];
    const float* Wcls = (const float*)d_in[8];
    const float* bcls = (const float*)d_in[9];
    const float* Wr   = (const float*)d_in[10];
    const float* br   = (const float*)d_in[11];
    float* out = (float*)d_out;
    float* ws  = (float*)d_ws;

    float* det_logit = ws + OFF_DET;
    float* cls_score = ws + OFF_CLS;
    float* ref0      = ws + OFF_REF0;
    float* ref1      = ws + OFF_REF1;
    float* mean_sc   = ws + OFF_MEAN;
    unsigned short* wpT = (unsigned short*)(ws + OFF_WPT);
    float* scal = ws + OFF_SCAL;
    int*   sel_idx = (int*)(ws + OFF_SELIDX);
    unsigned* hist = (unsigned*)(ws + OFF_HIST);

    hipLaunchKernelGGL(prep_kernel, dim3(1280), dim3(256), 0, stream,
                       Wa, Wb, Wcls, Wr, ba, bb, bcls, br, ws);
    hipLaunchKernelGGL(gemm_mfma, dim3(782), dim3(256), 0, stream,
                       h, wpT, ws + OFF_BPACK, Wc, bc,
                       det_logit, scal + SC_SUMEXP, cls_score, ref0, ref1, out + OUT_REF);
    hipLaunchKernelGGL(final_kernel, dim3(391), dim3(256), 0, stream,
                       det_logit, cls_score, lab, scal, out + OUT_FS, mean_sc, out);
    hipLaunchKernelGGL(hist_kernel, dim3(15, SELY), dim3(256), 0, stream,
                       out + OUT_FS, mean_sc, ref0, ref1, hist, scal, 21, 11);
    hipLaunchKernelGGL(hist_kernel, dim3(15, SELY), dim3(256), 0, stream,
                       out + OUT_FS, mean_sc, ref0, ref1, hist, scal, 10, 11);
    hipLaunchKernelGGL(hist_kernel, dim3(15, SELY), dim3(256), 0, stream,
                       out + OUT_FS, mean_sc, ref0, ref1, hist, scal, 0, 10);
    hipLaunchKernelGGL(collect_kernel, dim3(15, SELY), dim3(256), 0, stream,
                       out + OUT_FS, mean_sc, ref0, ref1, scal, sel_idx);
    hipLaunchKernelGGL(ce_kernel, dim3(240), dim3(256), 0, stream, h, Wr, br, sel_idx, scal);
    hipLaunchKernelGGL(loss_kernel, dim3(1), dim3(64), 0, stream, scal, out);
}